// Round 4
// baseline (457.972 us; speedup 1.0000x reference)
//
#include <hip/hip_runtime.h>

#define D 128
#define NLAYERS 5

using short8  = __attribute__((ext_vector_type(8))) short;
using short4v = __attribute__((ext_vector_type(4))) short;
using floatx4 = __attribute__((ext_vector_type(4))) float;

__device__ __forceinline__ unsigned bf16_rne(float x) {
    unsigned u = __float_as_uint(x);
    return (u + 0x7fffu + ((u >> 16) & 1u)) >> 16;
}
__device__ __forceinline__ float bf16_to_f32(short s) {
    return __uint_as_float(((unsigned)(unsigned short)s) << 16);
}

// ---------------- prep: W transpose/bf16 + edge histogram (deg zeroed by memset) ----------------
__global__ void prep_hist_kernel(const float* __restrict__ Wa, const float* __restrict__ Wb,
                                 const int* __restrict__ edst,
                                 short* __restrict__ wt, int* __restrict__ deg,
                                 int n_edges) {
    const int gtid = blockIdx.x * 256 + threadIdx.x;
    const int gsz  = gridDim.x * 256;
    for (int g = gtid; g < 2 * NLAYERS * D * D; g += gsz) {
        int mat = g >> 14, idx = g & 16383;
        int n = idx >> 7, k = idx & 127;
        const float* W = (mat & 1) ? (Wb + (size_t)(mat >> 1) * D * D)
                                   : (Wa + (size_t)(mat >> 1) * D * D);
        wt[g] = (short)bf16_rne(W[k * D + n]);
    }
    for (int e = gtid; e < n_edges; e += gsz) atomicAdd(&deg[edst[e]], 1);
}

#define SCAN_TILE 1024
__global__ void scan_sums_kernel(const int* __restrict__ deg, int* __restrict__ bsums, int n) {
    __shared__ int red[256];
    int base = blockIdx.x * SCAN_TILE + threadIdx.x * 4;
    int s = 0;
    #pragma unroll
    for (int j = 0; j < 4; j++) {
        int i = base + j;
        if (i < n) s += deg[i];
    }
    red[threadIdx.x] = s;
    __syncthreads();
    for (int off = 128; off > 0; off >>= 1) {
        if (threadIdx.x < off) red[threadIdx.x] += red[threadIdx.x + off];
        __syncthreads();
    }
    if (threadIdx.x == 0) bsums[blockIdx.x] = red[0];
}

__global__ void scan_bsums_kernel(int* __restrict__ bsums, int nblocks) {
    __shared__ int sdata[256];
    int carry = 0;
    for (int base = 0; base < nblocks; base += 256) {
        int i = base + threadIdx.x;
        int v = (i < nblocks) ? bsums[i] : 0;
        sdata[threadIdx.x] = v;
        __syncthreads();
        for (int off = 1; off < 256; off <<= 1) {
            int t = (threadIdx.x >= off) ? sdata[threadIdx.x - off] : 0;
            __syncthreads();
            sdata[threadIdx.x] += t;
            __syncthreads();
        }
        int incl = sdata[threadIdx.x];
        if (i < nblocks) bsums[i] = carry + incl - v;
        carry += sdata[255];
        __syncthreads();
    }
}

__global__ void scan_final_kernel(const int* __restrict__ deg, const int* __restrict__ bsums,
                                  int* __restrict__ offsets, int* __restrict__ cursor, int n) {
    __shared__ int sdata[256];
    int base = blockIdx.x * SCAN_TILE + threadIdx.x * 4;
    int v[4];
    int s = 0;
    #pragma unroll
    for (int j = 0; j < 4; j++) {
        int i = base + j;
        v[j] = (i < n) ? deg[i] : 0;
        s += v[j];
    }
    sdata[threadIdx.x] = s;
    __syncthreads();
    for (int off = 1; off < 256; off <<= 1) {
        int t = (threadIdx.x >= off) ? sdata[threadIdx.x - off] : 0;
        __syncthreads();
        sdata[threadIdx.x] += t;
        __syncthreads();
    }
    int excl = sdata[threadIdx.x] - s + bsums[blockIdx.x];
    #pragma unroll
    for (int j = 0; j < 4; j++) {
        int i = base + j;
        if (i <= n) offsets[i] = excl;
        if (i < n) cursor[i] = excl;
        excl += v[j];
    }
}

// ---------------- fused fill + H0 embedding gather (independent work, overlapped) ----------------
// gather part first (long-latency random reads start earliest), fill part after.
__global__ void fill_gather_kernel(const int* __restrict__ esrc, const int* __restrict__ edst,
                                   int* __restrict__ cursor, int* __restrict__ csr_src,
                                   const int* __restrict__ x, const float* __restrict__ emb,
                                   short* __restrict__ H0,
                                   int n_nodes, int n_edges) {
    const int t = blockIdx.x * 256 + threadIdx.x;
    const int gwork = n_nodes * 32;
    if (t < gwork) {
        int node = t >> 5, lane = t & 31;
        int s = x[node];
        const float4 v = *reinterpret_cast<const float4*>(emb + (size_t)s * D + lane * 4);
        short4v o;
        o[0] = (short)bf16_rne(v.x); o[1] = (short)bf16_rne(v.y);
        o[2] = (short)bf16_rne(v.z); o[3] = (short)bf16_rne(v.w);
        __builtin_nontemporal_store(o, reinterpret_cast<short4v*>(H0 + (size_t)node * D + lane * 4));
    } else {
        int e = t - gwork;
        if (e < n_edges) {
            int pos = atomicAdd(&cursor[edst[e]], 1);
            csr_src[pos] = esrc[e];
        }
    }
}

// ---------------- fused layer (R8-exact math) + optional fused pool on last layer ----------------
// block: 64 nodes, 512 threads (8 waves). Node-parallel aggregation, 8 lanes/node x 32B/lane,
// 4-way edge unroll. Time law (R0-R3): dur ~= FETCH / ~1.28 TB/s (L2-miss-path cap; occupancy
// and writes are ~free). So: NON-TEMPORAL hints on all streaming traffic (self-read, csr_src,
// h_out stores) to keep L2 lines for the random neighbor gather (the gather loads stay cached).
// LDS: zsh 16KB + ONE shared weight buffer 32KB = 48KB -> 3 blocks/CU.
// wb overwrites wa between GEMM1 and GEMM2 (hides under bias/relu VALU work).
// Last layer: h_out == nullptr, output only feeds the in-register pooled sum.
// 16B chunks XOR-swizzled: chunk c of row r at (c ^ (r&15)).
__global__ __launch_bounds__(512, 6) void layer_kernel(
        const int* __restrict__ offsets, const int* __restrict__ csr_src,
        const short* __restrict__ h_in, const short* __restrict__ wta,
        const short* __restrict__ wtb, const float* __restrict__ ba,
        const float* __restrict__ bb, short* __restrict__ h_out,
        float* __restrict__ pooled_accum, int n_rows) {
    __shared__ __align__(16) short zsh[64 * 128];     // z tile, then t tile, then pool scratch
    __shared__ __align__(16) short wsh[128 * 128];    // wa for GEMM1, then wb for GEMM2

    const int tid  = threadIdx.x;
    const int row0 = blockIdx.x * 64;

    #pragma unroll
    for (int i = 0; i < 4; i++) {
        int g = i * 512 + tid;
        int n = g >> 4, c = g & 15;
        int off = (n * 16 + (c ^ (n & 15))) * 8;
        *reinterpret_cast<short8*>(&wsh[off]) =
            *reinterpret_cast<const short8*>(wta + n * D + c * 8);
    }

    {
        const int r  = tid >> 3;
        const int l8 = tid & 7;
        const int gr = row0 + r;
        float acc[16];
        if (gr < n_rows) {
            const size_t cb = (size_t)gr * D + l8 * 16;
            short8 s0 = __builtin_nontemporal_load(reinterpret_cast<const short8*>(h_in + cb));
            short8 s1 = __builtin_nontemporal_load(reinterpret_cast<const short8*>(h_in + cb + 8));
            #pragma unroll
            for (int j = 0; j < 8; j++) { acc[j] = bf16_to_f32(s0[j]); acc[8 + j] = bf16_to_f32(s1[j]); }
            int beg = offsets[gr];
            int end = offsets[gr + 1];
            int e = beg;
            for (; e + 3 < end; e += 4) {
                int sA = __builtin_nontemporal_load(csr_src + e);
                int sB = __builtin_nontemporal_load(csr_src + e + 1);
                int sC = __builtin_nontemporal_load(csr_src + e + 2);
                int sD = __builtin_nontemporal_load(csr_src + e + 3);
                const short* pA = h_in + (size_t)sA * D + l8 * 16;
                const short* pB = h_in + (size_t)sB * D + l8 * 16;
                const short* pC = h_in + (size_t)sC * D + l8 * 16;
                const short* pD = h_in + (size_t)sD * D + l8 * 16;
                short8 a0 = *reinterpret_cast<const short8*>(pA);
                short8 a1 = *reinterpret_cast<const short8*>(pA + 8);
                short8 b0 = *reinterpret_cast<const short8*>(pB);
                short8 b1 = *reinterpret_cast<const short8*>(pB + 8);
                short8 c0 = *reinterpret_cast<const short8*>(pC);
                short8 c1 = *reinterpret_cast<const short8*>(pC + 8);
                short8 d0 = *reinterpret_cast<const short8*>(pD);
                short8 d1 = *reinterpret_cast<const short8*>(pD + 8);
                #pragma unroll
                for (int j = 0; j < 8; j++) {
                    acc[j]     += (bf16_to_f32(a0[j]) + bf16_to_f32(b0[j]))
                                + (bf16_to_f32(c0[j]) + bf16_to_f32(d0[j]));
                    acc[8 + j] += (bf16_to_f32(a1[j]) + bf16_to_f32(b1[j]))
                                + (bf16_to_f32(c1[j]) + bf16_to_f32(d1[j]));
                }
            }
            for (; e < end; e++) {
                int sA = __builtin_nontemporal_load(csr_src + e);
                const short* pA = h_in + (size_t)sA * D + l8 * 16;
                short8 a0 = *reinterpret_cast<const short8*>(pA);
                short8 a1 = *reinterpret_cast<const short8*>(pA + 8);
                #pragma unroll
                for (int j = 0; j < 8; j++) {
                    acc[j]     += bf16_to_f32(a0[j]);
                    acc[8 + j] += bf16_to_f32(a1[j]);
                }
            }
        } else {
            #pragma unroll
            for (int j = 0; j < 16; j++) acc[j] = 0.f;
        }
        short8 o0, o1;
        #pragma unroll
        for (int j = 0; j < 8; j++) { o0[j] = (short)bf16_rne(acc[j]); o1[j] = (short)bf16_rne(acc[8 + j]); }
        const int c0i = 2 * l8, c1i = 2 * l8 + 1;
        *reinterpret_cast<short8*>(&zsh[(r * 16 + (c0i ^ (r & 15))) * 8]) = o0;
        *reinterpret_cast<short8*>(&zsh[(r * 16 + (c1i ^ (r & 15))) * 8]) = o1;
    }
    __syncthreads();

    const int lane = tid & 63;
    const int wave = tid >> 6;
    const int wr   = wave >> 1;
    const int wc   = wave & 1;
    const int lm   = lane & 15;
    const int quad = lane >> 4;

    floatx4 acc1[4];
    #pragma unroll
    for (int b = 0; b < 4; b++) acc1[b] = floatx4{0.f, 0.f, 0.f, 0.f};
    {
        const int r = wr * 16 + lm;
        #pragma unroll
        for (int ks = 0; ks < 4; ks++) {
            const int c = ks * 4 + quad;
            short8 av = *reinterpret_cast<const short8*>(&zsh[(r * 16 + (c ^ (r & 15))) * 8]);
            #pragma unroll
            for (int cs = 0; cs < 4; cs++) {
                int nn = wc * 64 + cs * 16 + lm;
                short8 bv = *reinterpret_cast<const short8*>(&wsh[(nn * 16 + (c ^ (nn & 15))) * 8]);
                acc1[cs] = __builtin_amdgcn_mfma_f32_16x16x32_bf16(av, bv, acc1[cs], 0, 0, 0);
            }
        }
    }
    __syncthreads();   // all wa + z1 reads done; wsh and zsh may be overwritten

    // load wb over wa (L2-hot; hides under the bias/relu VALU work below)
    #pragma unroll
    for (int i = 0; i < 4; i++) {
        int g = i * 512 + tid;
        int n = g >> 4, c = g & 15;
        int off = (n * 16 + (c ^ (n & 15))) * 8;
        *reinterpret_cast<short8*>(&wsh[off]) =
            *reinterpret_cast<const short8*>(wtb + n * D + c * 8);
    }

    #pragma unroll
    for (int cs = 0; cs < 4; cs++) {
        int col = wc * 64 + cs * 16 + lm;
        float bva = ba[col];
        int cj = col >> 3, ci = col & 7;
        #pragma unroll
        for (int reg = 0; reg < 4; reg++) {
            int r = wr * 16 + quad * 4 + reg;
            float v = fmaxf(acc1[cs][reg] + bva, 0.f);
            zsh[(r * 16 + (cj ^ (r & 15))) * 8 + ci] = (short)bf16_rne(v);
        }
    }
    __syncthreads();

    floatx4 acc2[4];
    #pragma unroll
    for (int b = 0; b < 4; b++) acc2[b] = floatx4{0.f, 0.f, 0.f, 0.f};
    {
        const int r = wr * 16 + lm;
        #pragma unroll
        for (int ks = 0; ks < 4; ks++) {
            const int c = ks * 4 + quad;
            short8 av = *reinterpret_cast<const short8*>(&zsh[(r * 16 + (c ^ (r & 15))) * 8]);
            #pragma unroll
            for (int cs = 0; cs < 4; cs++) {
                int nn = wc * 64 + cs * 16 + lm;
                short8 bv = *reinterpret_cast<const short8*>(&wsh[(nn * 16 + (c ^ (nn & 15))) * 8]);
                acc2[cs] = __builtin_amdgcn_mfma_f32_16x16x32_bf16(av, bv, acc2[cs], 0, 0, 0);
            }
        }
    }

    float psum[4];   // per-thread, per-cs column partial (only used on last layer)
    #pragma unroll
    for (int cs = 0; cs < 4; cs++) {
        int col = wc * 64 + cs * 16 + lm;
        float bvb = bb[col];
        float s = 0.f;
        #pragma unroll
        for (int reg = 0; reg < 4; reg++) {
            int r = row0 + wr * 16 + quad * 4 + reg;
            if (r < n_rows) {
                float v = fmaxf(acc2[cs][reg] + bvb, 0.f);
                short hv = (short)bf16_rne(v);      // round exactly as if stored (R8 pool semantics)
                if (h_out != nullptr)
                    __builtin_nontemporal_store(hv, h_out + (size_t)r * D + col);
                s += bf16_to_f32(hv);
            }
        }
        psum[cs] = s;
    }

    if (pooled_accum != nullptr) {
        __syncthreads();                 // all gemm2 zsh reads done; reuse zsh as f32 scratch
        float* part = (float*)zsh;       // [16][128] floats = 8KB
        #pragma unroll
        for (int cs = 0; cs < 4; cs++)
            part[(wr * 4 + quad) * 128 + wc * 64 + cs * 16 + lm] = psum[cs];
        __syncthreads();
        if (tid < 128) {
            float s = 0.f;
            #pragma unroll
            for (int g = 0; g < 16; g++) s += part[g * 128 + tid];
            atomicAdd(&pooled_accum[tid], s);
        }
    }
}

// ---------------- final linear (fp32 exact) ----------------
__global__ void final_kernel(const float* __restrict__ pooled, const float* __restrict__ Wlin,
                             const float* __restrict__ blin, float* __restrict__ out) {
    const int j = threadIdx.x;
    __shared__ float p[D];
    p[j] = pooled[j];
    __syncthreads();
    float s = blin[j];
    #pragma unroll 8
    for (int k = 0; k < D; k++) s += p[k] * Wlin[k * D + j];
    out[j] = s;
}

extern "C" void kernel_launch(void* const* d_in, const int* in_sizes, int n_in,
                              void* d_out, int out_size, void* d_ws, size_t ws_size,
                              hipStream_t stream) {
    const int*   x    = (const int*)d_in[0];
    const int*   ei   = (const int*)d_in[1];
    const float* emb  = (const float*)d_in[2];
    const float* Wa   = (const float*)d_in[3];
    const float* ba   = (const float*)d_in[4];
    const float* Wb   = (const float*)d_in[5];
    const float* bb   = (const float*)d_in[6];
    const float* Wlin = (const float*)d_in[7];
    const float* blin = (const float*)d_in[8];
    float* out = (float*)d_out;

    const int N = in_sizes[0];
    const int E = in_sizes[1] / 2;
    const int* esrc = ei;
    const int* edst = ei + E;

    // workspace: H0 | H1 (bf16) | pooled | deg | offsets | cursor | bsums | csr_src | wt
    short* H0 = (short*)d_ws;                       // N*D
    short* H1 = H0 + (size_t)N * D;                 // N*D
    float* pooled = (float*)(H1 + (size_t)N * D);   // 128
    int* deg     = (int*)(pooled + 128);            // N
    int* offsets = deg + N;                         // N+1
    int* cursor  = offsets + (N + 1);               // N
    int* bsums   = cursor + N;                      // 4096
    int* csr_src = bsums + 4096;                    // E
    uintptr_t wt_addr = ((uintptr_t)(csr_src + E) + 15) & ~(uintptr_t)15;
    short* wt = (short*)wt_addr;                    // [10][128][128] bf16

    const int scan_blocks = (N + 1 + SCAN_TILE - 1) / SCAN_TILE;

    // zero pooled[128] + deg[N] in one contiguous memset (graph-capture-safe)
    hipMemsetAsync(pooled, 0, (size_t)(128 + N) * sizeof(int), stream);

    prep_hist_kernel<<<1024, 256, 0, stream>>>(Wa, Wb, edst, wt, deg, E);
    scan_sums_kernel<<<scan_blocks, 256, 0, stream>>>(deg, bsums, N);
    scan_bsums_kernel<<<1, 256, 0, stream>>>(bsums, scan_blocks);
    scan_final_kernel<<<scan_blocks, 256, 0, stream>>>(deg, bsums, offsets, cursor, N);

    const int fg_threads = N * 32 + E;
    fill_gather_kernel<<<(fg_threads + 255) / 256, 256, 0, stream>>>(
        esrc, edst, cursor, csr_src, x, emb, H0, N, E);

    const int layer_blocks = (N + 63) / 64;
    short* hin = H0; short* hout = H1;
    for (int l = 0; l < NLAYERS; l++) {
        const bool last = (l == NLAYERS - 1);
        float* pacc = last ? pooled : nullptr;
        short* hdst = last ? nullptr : hout;   // last layer: output only feeds the pool
        layer_kernel<<<layer_blocks, 512, 0, stream>>>(
            offsets, csr_src, hin,
            wt + (size_t)(2 * l) * D * D, wt + (size_t)(2 * l + 1) * D * D,
            ba + (size_t)l * D, bb + (size_t)l * D, hdst, pacc, N);
        short* tmp = hin; hin = hout; hout = tmp;
    }

    final_kernel<<<1, 128, 0, stream>>>(pooled, Wlin, blin, out);
}

// Round 5
// 379.226 us; speedup vs baseline: 1.2076x; 1.2076x over previous
//
#include <hip/hip_runtime.h>

#define D 128
#define NLAYERS 5

using short8  = __attribute__((ext_vector_type(8))) short;
using short4v = __attribute__((ext_vector_type(4))) short;
using floatx4 = __attribute__((ext_vector_type(4))) float;
using floatx2 = __attribute__((ext_vector_type(2))) float;

__device__ __forceinline__ unsigned bf16_rne(float x) {
    unsigned u = __float_as_uint(x);
    return (u + 0x7fffu + ((u >> 16) & 1u)) >> 16;
}
__device__ __forceinline__ float bf16_to_f32(short s) {
    return __uint_as_float(((unsigned)(unsigned short)s) << 16);
}

// H is stored as fp8 e4m3 with a fixed x16 scale (power of 2 => scaling is exact).
// h values are O(0.02-1): x16 puts them in e4m3's normal range (0.3-16, max 448).
#define HSCALE 16.0f
#define HSCALE_INV 0.0625f

// ---------------- prepA: W transpose/bf16 + H0 gather (fp8) + fused edge histogram ----------------
// deg/pooled zeroed by hipMemsetAsync before this kernel.
__global__ void prepA_kernel(const int* __restrict__ x, const float* __restrict__ emb,
                             const float* __restrict__ Wa, const float* __restrict__ Wb,
                             const int* __restrict__ edst,
                             unsigned char* __restrict__ H0, short* __restrict__ wt,
                             int* __restrict__ deg,
                             int n_nodes, int n_edges) {
    const int gtid = blockIdx.x * 256 + threadIdx.x;
    const int gsz  = gridDim.x * 256;
    for (int g = gtid; g < 2 * NLAYERS * D * D; g += gsz) {
        int mat = g >> 14, idx = g & 16383;
        int n = idx >> 7, k = idx & 127;
        const float* W = (mat & 1) ? (Wb + (size_t)(mat >> 1) * D * D)
                                   : (Wa + (size_t)(mat >> 1) * D * D);
        wt[g] = (short)bf16_rne(W[k * D + n]);
    }
    for (int t = gtid; t < n_nodes * 32; t += gsz) {
        int node = t >> 5, lane = t & 31;
        int s = x[node];
        const float4 v = *reinterpret_cast<const float4*>(emb + (size_t)s * D + lane * 4);
        int w = __builtin_amdgcn_cvt_pk_fp8_f32(v.x * HSCALE, v.y * HSCALE, 0, false);
        w = __builtin_amdgcn_cvt_pk_fp8_f32(v.z * HSCALE, v.w * HSCALE, w, true);
        reinterpret_cast<unsigned int*>(H0)[(size_t)node * 32 + lane] = (unsigned int)w;
    }
    for (int e = gtid; e < n_edges; e += gsz) atomicAdd(&deg[edst[e]], 1);
}

#define SCAN_TILE 1024
__global__ void scan_sums_kernel(const int* __restrict__ deg, int* __restrict__ bsums, int n) {
    __shared__ int red[256];
    int base = blockIdx.x * SCAN_TILE + threadIdx.x * 4;
    int s = 0;
    #pragma unroll
    for (int j = 0; j < 4; j++) {
        int i = base + j;
        if (i < n) s += deg[i];
    }
    red[threadIdx.x] = s;
    __syncthreads();
    for (int off = 128; off > 0; off >>= 1) {
        if (threadIdx.x < off) red[threadIdx.x] += red[threadIdx.x + off];
        __syncthreads();
    }
    if (threadIdx.x == 0) bsums[blockIdx.x] = red[0];
}

__global__ void scan_bsums_kernel(int* __restrict__ bsums, int nblocks) {
    __shared__ int sdata[256];
    int carry = 0;
    for (int base = 0; base < nblocks; base += 256) {
        int i = base + threadIdx.x;
        int v = (i < nblocks) ? bsums[i] : 0;
        sdata[threadIdx.x] = v;
        __syncthreads();
        for (int off = 1; off < 256; off <<= 1) {
            int t = (threadIdx.x >= off) ? sdata[threadIdx.x - off] : 0;
            __syncthreads();
            sdata[threadIdx.x] += t;
            __syncthreads();
        }
        int incl = sdata[threadIdx.x];
        if (i < nblocks) bsums[i] = carry + incl - v;
        carry += sdata[255];
        __syncthreads();
    }
}

__global__ void scan_final_kernel(const int* __restrict__ deg, const int* __restrict__ bsums,
                                  int* __restrict__ offsets, int* __restrict__ cursor, int n) {
    __shared__ int sdata[256];
    int base = blockIdx.x * SCAN_TILE + threadIdx.x * 4;
    int v[4];
    int s = 0;
    #pragma unroll
    for (int j = 0; j < 4; j++) {
        int i = base + j;
        v[j] = (i < n) ? deg[i] : 0;
        s += v[j];
    }
    sdata[threadIdx.x] = s;
    __syncthreads();
    for (int off = 1; off < 256; off <<= 1) {
        int t = (threadIdx.x >= off) ? sdata[threadIdx.x - off] : 0;
        __syncthreads();
        sdata[threadIdx.x] += t;
        __syncthreads();
    }
    int excl = sdata[threadIdx.x] - s + bsums[blockIdx.x];
    #pragma unroll
    for (int j = 0; j < 4; j++) {
        int i = base + j;
        if (i <= n) offsets[i] = excl;
        if (i < n) cursor[i] = excl;
        excl += v[j];
    }
}

__global__ void fill_kernel(const int* __restrict__ esrc, const int* __restrict__ edst,
                            int* __restrict__ cursor, int* __restrict__ csr_src, int n_edges) {
    int e = blockIdx.x * 256 + threadIdx.x;
    if (e >= n_edges) return;
    int pos = atomicAdd(&cursor[edst[e]], 1);
    csr_src[pos] = esrc[e];
}

// ---------------- fused layer + optional fused pool on last layer ----------------
// Time law (R0-R4): dur ~= FETCH / ~1.28 TB/s (L2-miss-path cap; writes & occupancy ~free;
// NT hints hurt). So this round cuts BYTES: H stored as fp8 e4m3 (row = 128B, was 256B bf16).
// Halves self-read + gather-miss bytes AND doubles L2 row residency. GEMMs stay bf16 exactly
// as before (z = sum of fp8-decoded values, rounded to bf16; weights bf16; pool f32).
// block: 64 nodes, 512 threads. Aggregation: 8 lanes/node x 16B/lane (one uint4 = 16 fp8/lane),
// 4-way edge unroll. LDS: zsh 16KB + one weight buffer 32KB = 48KB -> 3 blocks/CU.
// wb overwrites wa between GEMM1 and GEMM2. Last layer: h_out == nullptr (pool-only).
// zsh 16B chunks XOR-swizzled: chunk c of row r at (c ^ (r&15)).
__global__ __launch_bounds__(512, 6) void layer_kernel(
        const int* __restrict__ offsets, const int* __restrict__ csr_src,
        const unsigned char* __restrict__ h_in, const short* __restrict__ wta,
        const short* __restrict__ wtb, const float* __restrict__ ba,
        const float* __restrict__ bb, unsigned char* __restrict__ h_out,
        float* __restrict__ pooled_accum, int n_rows) {
    __shared__ __align__(16) short zsh[64 * 128];     // z tile, then t tile, then pool scratch
    __shared__ __align__(16) short wsh[128 * 128];    // wa for GEMM1, then wb for GEMM2

    const int tid  = threadIdx.x;
    const int row0 = blockIdx.x * 64;

    #pragma unroll
    for (int i = 0; i < 4; i++) {
        int g = i * 512 + tid;
        int n = g >> 4, c = g & 15;
        int off = (n * 16 + (c ^ (n & 15))) * 8;
        *reinterpret_cast<short8*>(&wsh[off]) =
            *reinterpret_cast<const short8*>(wta + n * D + c * 8);
    }

    {
        const int r  = tid >> 3;
        const int l8 = tid & 7;
        const int gr = row0 + r;
        float acc[16];
        if (gr < n_rows) {
            {   // self
                uint4 w = *reinterpret_cast<const uint4*>(h_in + (size_t)gr * D + l8 * 16);
                unsigned int wd[4] = {w.x, w.y, w.z, w.w};
                #pragma unroll
                for (int k = 0; k < 4; k++) {
                    floatx2 lo = __builtin_amdgcn_cvt_pk_f32_fp8((int)wd[k], false);
                    floatx2 hi = __builtin_amdgcn_cvt_pk_f32_fp8((int)wd[k], true);
                    acc[4 * k]     = lo[0]; acc[4 * k + 1] = lo[1];
                    acc[4 * k + 2] = hi[0]; acc[4 * k + 3] = hi[1];
                }
            }
            int beg = offsets[gr];
            int end = offsets[gr + 1];
            int e = beg;
            for (; e + 3 < end; e += 4) {
                int sA = csr_src[e];
                int sB = csr_src[e + 1];
                int sC = csr_src[e + 2];
                int sD = csr_src[e + 3];
                uint4 wA = *reinterpret_cast<const uint4*>(h_in + (size_t)sA * D + l8 * 16);
                uint4 wB = *reinterpret_cast<const uint4*>(h_in + (size_t)sB * D + l8 * 16);
                uint4 wC = *reinterpret_cast<const uint4*>(h_in + (size_t)sC * D + l8 * 16);
                uint4 wD = *reinterpret_cast<const uint4*>(h_in + (size_t)sD * D + l8 * 16);
                unsigned int da[4] = {wA.x, wA.y, wA.z, wA.w};
                unsigned int db[4] = {wB.x, wB.y, wB.z, wB.w};
                unsigned int dc[4] = {wC.x, wC.y, wC.z, wC.w};
                unsigned int dd[4] = {wD.x, wD.y, wD.z, wD.w};
                #pragma unroll
                for (int k = 0; k < 4; k++) {
                    floatx2 alo = __builtin_amdgcn_cvt_pk_f32_fp8((int)da[k], false);
                    floatx2 ahi = __builtin_amdgcn_cvt_pk_f32_fp8((int)da[k], true);
                    floatx2 blo = __builtin_amdgcn_cvt_pk_f32_fp8((int)db[k], false);
                    floatx2 bhi = __builtin_amdgcn_cvt_pk_f32_fp8((int)db[k], true);
                    floatx2 clo = __builtin_amdgcn_cvt_pk_f32_fp8((int)dc[k], false);
                    floatx2 chi = __builtin_amdgcn_cvt_pk_f32_fp8((int)dc[k], true);
                    floatx2 dlo = __builtin_amdgcn_cvt_pk_f32_fp8((int)dd[k], false);
                    floatx2 dhi = __builtin_amdgcn_cvt_pk_f32_fp8((int)dd[k], true);
                    acc[4 * k]     += (alo[0] + blo[0]) + (clo[0] + dlo[0]);
                    acc[4 * k + 1] += (alo[1] + blo[1]) + (clo[1] + dlo[1]);
                    acc[4 * k + 2] += (ahi[0] + bhi[0]) + (chi[0] + dhi[0]);
                    acc[4 * k + 3] += (ahi[1] + bhi[1]) + (chi[1] + dhi[1]);
                }
            }
            for (; e < end; e++) {
                int sA = csr_src[e];
                uint4 wA = *reinterpret_cast<const uint4*>(h_in + (size_t)sA * D + l8 * 16);
                unsigned int da[4] = {wA.x, wA.y, wA.z, wA.w};
                #pragma unroll
                for (int k = 0; k < 4; k++) {
                    floatx2 alo = __builtin_amdgcn_cvt_pk_f32_fp8((int)da[k], false);
                    floatx2 ahi = __builtin_amdgcn_cvt_pk_f32_fp8((int)da[k], true);
                    acc[4 * k]     += alo[0];
                    acc[4 * k + 1] += alo[1];
                    acc[4 * k + 2] += ahi[0];
                    acc[4 * k + 3] += ahi[1];
                }
            }
        } else {
            #pragma unroll
            for (int j = 0; j < 16; j++) acc[j] = 0.f;
        }
        // undo the x16 storage scale once on the sum (power-of-2: exact)
        short8 o0, o1;
        #pragma unroll
        for (int j = 0; j < 8; j++) {
            o0[j] = (short)bf16_rne(acc[j] * HSCALE_INV);
            o1[j] = (short)bf16_rne(acc[8 + j] * HSCALE_INV);
        }
        const int c0i = 2 * l8, c1i = 2 * l8 + 1;
        *reinterpret_cast<short8*>(&zsh[(r * 16 + (c0i ^ (r & 15))) * 8]) = o0;
        *reinterpret_cast<short8*>(&zsh[(r * 16 + (c1i ^ (r & 15))) * 8]) = o1;
    }
    __syncthreads();

    const int lane = tid & 63;
    const int wave = tid >> 6;
    const int wr   = wave >> 1;
    const int wc   = wave & 1;
    const int lm   = lane & 15;
    const int quad = lane >> 4;

    floatx4 acc1[4];
    #pragma unroll
    for (int b = 0; b < 4; b++) acc1[b] = floatx4{0.f, 0.f, 0.f, 0.f};
    {
        const int r = wr * 16 + lm;
        #pragma unroll
        for (int ks = 0; ks < 4; ks++) {
            const int c = ks * 4 + quad;
            short8 av = *reinterpret_cast<const short8*>(&zsh[(r * 16 + (c ^ (r & 15))) * 8]);
            #pragma unroll
            for (int cs = 0; cs < 4; cs++) {
                int nn = wc * 64 + cs * 16 + lm;
                short8 bv = *reinterpret_cast<const short8*>(&wsh[(nn * 16 + (c ^ (nn & 15))) * 8]);
                acc1[cs] = __builtin_amdgcn_mfma_f32_16x16x32_bf16(av, bv, acc1[cs], 0, 0, 0);
            }
        }
    }
    __syncthreads();   // all wa + z1 reads done; wsh and zsh may be overwritten

    // load wb over wa (L2-hot; hides under the bias/relu VALU work below)
    #pragma unroll
    for (int i = 0; i < 4; i++) {
        int g = i * 512 + tid;
        int n = g >> 4, c = g & 15;
        int off = (n * 16 + (c ^ (n & 15))) * 8;
        *reinterpret_cast<short8*>(&wsh[off]) =
            *reinterpret_cast<const short8*>(wtb + n * D + c * 8);
    }

    #pragma unroll
    for (int cs = 0; cs < 4; cs++) {
        int col = wc * 64 + cs * 16 + lm;
        float bva = ba[col];
        int cj = col >> 3, ci = col & 7;
        #pragma unroll
        for (int reg = 0; reg < 4; reg++) {
            int r = wr * 16 + quad * 4 + reg;
            float v = fmaxf(acc1[cs][reg] + bva, 0.f);
            zsh[(r * 16 + (cj ^ (r & 15))) * 8 + ci] = (short)bf16_rne(v);
        }
    }
    __syncthreads();

    floatx4 acc2[4];
    #pragma unroll
    for (int b = 0; b < 4; b++) acc2[b] = floatx4{0.f, 0.f, 0.f, 0.f};
    {
        const int r = wr * 16 + lm;
        #pragma unroll
        for (int ks = 0; ks < 4; ks++) {
            const int c = ks * 4 + quad;
            short8 av = *reinterpret_cast<const short8*>(&zsh[(r * 16 + (c ^ (r & 15))) * 8]);
            #pragma unroll
            for (int cs = 0; cs < 4; cs++) {
                int nn = wc * 64 + cs * 16 + lm;
                short8 bv = *reinterpret_cast<const short8*>(&wsh[(nn * 16 + (c ^ (nn & 15))) * 8]);
                acc2[cs] = __builtin_amdgcn_mfma_f32_16x16x32_bf16(av, bv, acc2[cs], 0, 0, 0);
            }
        }
    }

    float psum[4];   // per-thread, per-cs column partial (only used on last layer)
    #pragma unroll
    for (int cs = 0; cs < 4; cs++) {
        int col = wc * 64 + cs * 16 + lm;
        float bvb = bb[col];
        float s = 0.f;
        #pragma unroll
        for (int reg = 0; reg < 4; reg++) {
            int r = row0 + wr * 16 + quad * 4 + reg;
            if (r < n_rows) {
                float v = fmaxf(acc2[cs][reg] + bvb, 0.f);
                if (h_out != nullptr) {
                    float sv = v * HSCALE;
                    int pw = __builtin_amdgcn_cvt_pk_fp8_f32(sv, sv, 0, false);
                    h_out[(size_t)r * D + col] = (unsigned char)(pw & 0xff);
                }
                s += v;   // pool the f32 value (last layer stores nothing)
            }
        }
        psum[cs] = s;
    }

    if (pooled_accum != nullptr) {
        __syncthreads();                 // all gemm2 zsh reads done; reuse zsh as f32 scratch
        float* part = (float*)zsh;       // [16][128] floats = 8KB
        #pragma unroll
        for (int cs = 0; cs < 4; cs++)
            part[(wr * 4 + quad) * 128 + wc * 64 + cs * 16 + lm] = psum[cs];
        __syncthreads();
        if (tid < 128) {
            float s = 0.f;
            #pragma unroll
            for (int g = 0; g < 16; g++) s += part[g * 128 + tid];
            atomicAdd(&pooled_accum[tid], s);
        }
    }
}

// ---------------- final linear (fp32 exact) ----------------
__global__ void final_kernel(const float* __restrict__ pooled, const float* __restrict__ Wlin,
                             const float* __restrict__ blin, float* __restrict__ out) {
    const int j = threadIdx.x;
    __shared__ float p[D];
    p[j] = pooled[j];
    __syncthreads();
    float s = blin[j];
    #pragma unroll 8
    for (int k = 0; k < D; k++) s += p[k] * Wlin[k * D + j];
    out[j] = s;
}

extern "C" void kernel_launch(void* const* d_in, const int* in_sizes, int n_in,
                              void* d_out, int out_size, void* d_ws, size_t ws_size,
                              hipStream_t stream) {
    const int*   x    = (const int*)d_in[0];
    const int*   ei   = (const int*)d_in[1];
    const float* emb  = (const float*)d_in[2];
    const float* Wa   = (const float*)d_in[3];
    const float* ba   = (const float*)d_in[4];
    const float* Wb   = (const float*)d_in[5];
    const float* bb   = (const float*)d_in[6];
    const float* Wlin = (const float*)d_in[7];
    const float* blin = (const float*)d_in[8];
    float* out = (float*)d_out;

    const int N = in_sizes[0];
    const int E = in_sizes[1] / 2;
    const int* esrc = ei;
    const int* edst = ei + E;

    // workspace: H0 | H1 (fp8, N*128 bytes each) | pooled | deg | offsets | cursor | bsums | csr_src | wt
    unsigned char* H0 = (unsigned char*)d_ws;           // N*128 bytes
    unsigned char* H1 = H0 + (size_t)N * D;             // N*128 bytes
    float* pooled = (float*)(H1 + (size_t)N * D);       // 128
    int* deg     = (int*)(pooled + 128);                // N
    int* offsets = deg + N;                             // N+1
    int* cursor  = offsets + (N + 1);                   // N
    int* bsums   = cursor + N;                          // 4096
    int* csr_src = bsums + 4096;                        // E
    uintptr_t wt_addr = ((uintptr_t)(csr_src + E) + 15) & ~(uintptr_t)15;
    short* wt = (short*)wt_addr;                        // [10][128][128] bf16

    const int scan_blocks = (N + 1 + SCAN_TILE - 1) / SCAN_TILE;

    // zero pooled[128] + deg[N] in one contiguous memset (graph-capture-safe)
    hipMemsetAsync(pooled, 0, (size_t)(128 + N) * sizeof(int), stream);

    prepA_kernel<<<1024, 256, 0, stream>>>(x, emb, Wa, Wb, edst, H0, wt, deg, N, E);
    scan_sums_kernel<<<scan_blocks, 256, 0, stream>>>(deg, bsums, N);
    scan_bsums_kernel<<<1, 256, 0, stream>>>(bsums, scan_blocks);
    scan_final_kernel<<<scan_blocks, 256, 0, stream>>>(deg, bsums, offsets, cursor, N);
    fill_kernel<<<(E + 255) / 256, 256, 0, stream>>>(esrc, edst, cursor, csr_src, E);

    const int layer_blocks = (N + 63) / 64;
    unsigned char* hin = H0; unsigned char* hout = H1;
    for (int l = 0; l < NLAYERS; l++) {
        const bool last = (l == NLAYERS - 1);
        float* pacc = last ? pooled : nullptr;
        unsigned char* hdst = last ? nullptr : hout;   // last layer: output only feeds the pool
        layer_kernel<<<layer_blocks, 512, 0, stream>>>(
            offsets, csr_src, hin,
            wt + (size_t)(2 * l) * D * D, wt + (size_t)(2 * l + 1) * D * D,
            ba + (size_t)l * D, bb + (size_t)l * D, hdst, pacc, N);
        unsigned char* tmp = hin; hin = hout; hout = tmp;
    }

    final_kernel<<<1, 128, 0, stream>>>(pooled, Wlin, blin, out);
}